// Round 9
// baseline (1040.606 us; speedup 1.0000x reference)
//
#include <hip/hip_runtime.h>
#include <hip/hip_bf16.h>
#include <math.h>

typedef __attribute__((ext_vector_type(8))) short short8;
typedef __attribute__((ext_vector_type(4))) float floatx4;

__device__ __forceinline__ float bf2f(unsigned short u) {
    union { unsigned int i; float f; } v;
    v.i = ((unsigned int)u) << 16;
    return v.f;
}
__device__ __forceinline__ unsigned short f2bf(float f) {
    union { float f; unsigned int i; } v;
    v.f = f;
    return (unsigned short)((v.i + 0x7FFFu + ((v.i >> 16) & 1u)) >> 16);
}
__device__ __forceinline__ void async16(const void* g, void* l) {
    __builtin_amdgcn_global_load_lds((const __attribute__((address_space(1))) void*)g,
                                     (__attribute__((address_space(3))) void*)l, 16, 0, 0);
}

// ---------------- fp32 -> bf16 convert (optional head-scale on first `cut` elems) ----
__global__ __launch_bounds__(256) void cvt_kernel(const float* __restrict__ s,
                                                  unsigned short* __restrict__ d, int n,
                                                  int cut, float scale) {
    int i = blockIdx.x * 256 + threadIdx.x;
    if (i < n) d[i] = f2bf(s[i] * (i < cut ? scale : 1.0f));
}
__global__ __launch_bounds__(256) void biasscale_kernel(const float* __restrict__ s,
                                                        float* __restrict__ d, int n,
                                                        int cut, float scale) {
    int i = blockIdx.x * 256 + threadIdx.x;
    if (i < n) d[i] = s[i] * (i < cut ? scale : 1.0f);
}

// ---------------- bias+mask accumulator-init table ----------------
// tbl[cls][h][query 64][key 64] fp32. key>=49 -> -3e38 (pad), query>=49 -> 0 (unused).
// cls = (wh==7)*2 + (ww==7): mask regions only differ at the bottom/right window row/col.
__global__ __launch_bounds__(256) void bmt_kernel(const float* __restrict__ btab,
                                                  float* __restrict__ tbl) {
    int idx = blockIdx.x * 256 + threadIdx.x;  // < 4*6*64*64
    int key = idx & 63;
    int q = (idx >> 6) & 63;
    int h = (idx >> 12) % 6;
    int cls = idx / (4096 * 6);
    float v;
    if (key >= 49) v = -3.0e38f;
    else if (q >= 49) v = 0.0f;
    else {
        int qi = q / 7, qj = q % 7, ki = key / 7, kj = key % 7;
        v = btab[((qi - ki + 6) * 13 + (qj - kj + 6)) * 6 + h];
        int whT = (cls >> 1) & 1, wwT = cls & 1;
        int rq = (whT ? (qi < 4 ? 1 : 2) : 0) * 3 + (wwT ? (qj < 4 ? 1 : 2) : 0);
        int rk = (whT ? (ki < 4 ? 1 : 2) : 0) * 3 + (wwT ? (kj < 4 ? 1 : 2) : 0);
        if (rq != rk) v -= 100.0f;
    }
    tbl[idx] = v;
}

// ---------------- LayerNorm over C=192, one wave per row ----------------
__global__ __launch_bounds__(256) void ln_kernel(const float* __restrict__ src,
                                                 const float* __restrict__ gw,
                                                 const float* __restrict__ bw,
                                                 unsigned short* __restrict__ dst,
                                                 int mode) {
    int o = blockIdx.x * 4 + (threadIdx.x >> 6);
    int lane = threadIdx.x & 63;
    size_t srow;
    if (mode == 0) {
        int win = o / 49, n = o % 49;
        int b = win >> 6, wl = win & 63;
        int wh = wl >> 3, ww = wl & 7;
        int i = n / 7, j = n % 7;
        int pr = (wh * 7 + i + 3) % 56;   // roll(-3)
        int pc = (ww * 7 + j + 3) % 56;
        srow = ((size_t)b * 3136 + (size_t)(pr * 56 + pc)) * 192;
    } else {
        srow = (size_t)o * 192;
    }
    float v0 = src[srow + lane];
    float v1 = src[srow + lane + 64];
    float v2 = src[srow + lane + 128];
    float s = v0 + v1 + v2;
    float s2 = v0 * v0 + v1 * v1 + v2 * v2;
    #pragma unroll
    for (int off = 32; off > 0; off >>= 1) {
        s += __shfl_xor(s, off);
        s2 += __shfl_xor(s2, off);
    }
    float mean = s * (1.0f / 192.0f);
    float var = s2 * (1.0f / 192.0f) - mean * mean;
    float inv = rsqrtf(var + 1e-5f);
    size_t drow = (size_t)o * 192;
    dst[drow + lane]       = f2bf((v0 - mean) * inv * gw[lane]       + bw[lane]);
    dst[drow + lane + 64]  = f2bf((v1 - mean) * inv * gw[lane + 64]  + bw[lane + 64]);
    dst[drow + lane + 128] = f2bf((v2 - mean) * inv * gw[lane + 128] + bw[lane + 128]);
}

// ---------------- GEMM: C[m][n] = sum_k A[m][k]*W[n][k] (+bias, epilogue) ----------
// R8 structure (measured best: 12KB LDS single-buffer, 2 syncs/step, XCD-grouping
// swizzle -> qkv FETCH 314->38.5MB). ONE change vs R8: both-sides XOR swizzle on the
// LDS K-slots (rule #21: global_load_lds writes linearly, so the SOURCE slot is
// pre-swizzled: scol = ((lane&3)^(srow&3)); the READ slot applies the same XOR:
// rc = (quad^(l15&3))). Turns the 8-way ds_read_b128 bank conflict (R8 counter:
// SQ_LDS_BANK_CONFLICT=8.1M/dispatch) into the free 2-lanes/bank pattern.
template <int EPI>
__global__ __launch_bounds__(256) void gemm_nt(const unsigned short* __restrict__ A,
                                               const unsigned short* __restrict__ W,
                                               const float* __restrict__ bias,
                                               int K, int ldo, int mbase, int gx,
                                               unsigned short* __restrict__ outb,
                                               float* __restrict__ outf,
                                               const float* __restrict__ resid) {
    __shared__ __align__(16) unsigned short Al[128][32];
    __shared__ __align__(16) unsigned short Wl[64][32];
    int tid = threadIdx.x;
    int lane = tid & 63;
    int wv = tid >> 6;
    int wm = wv >> 1, wn = wv & 1;
    // XCD-grouping swizzle: per-XCD contiguous virtual id (grid always % 8 == 0)
    int bid = blockIdx.x;
    int v = (bid & 7) * ((int)gridDim.x >> 3) + (bid >> 3);
    int m0 = (v / gx) * 128;
    int n0 = (v % gx) * 64;
    int quad = lane >> 4, l15 = lane & 15;

    int srow = lane >> 2;
    int scol = ((lane & 3) ^ (srow & 3)) * 8;   // pre-swizzled global source K-slot
    const unsigned short* aP0 = A + (size_t)(m0 + wv * 32 + srow) * K + scol;
    const unsigned short* aP1 = aP0 + (size_t)16 * K;
    const unsigned short* wP  = W + (size_t)(n0 + wv * 16 + srow) * K + scol;
    unsigned short* lA0 = &Al[wv * 32][0];
    unsigned short* lA1 = &Al[wv * 32 + 16][0];
    unsigned short* lW  = &Wl[wv * 16][0];

    floatx4 acc[4][2];
    floatx4 zero = {0.f, 0.f, 0.f, 0.f};
    #pragma unroll
    for (int a = 0; a < 4; ++a)
        #pragma unroll
        for (int b = 0; b < 2; ++b) acc[a][b] = zero;

    int rc = (quad ^ (l15 & 3)) * 8;            // swizzled read K-slot
    for (int kt = 0; kt < K; kt += 32) {
        __syncthreads();
        async16(aP0 + kt, lA0);
        async16(aP1 + kt, lA1);
        async16(wP + kt, lW);
        __syncthreads();
        short8 af[4], wf[2];
        #pragma unroll
        for (int mt = 0; mt < 4; ++mt)
            af[mt] = *(const short8*)&Al[wm * 64 + mt * 16 + l15][rc];
        #pragma unroll
        for (int nt = 0; nt < 2; ++nt)
            wf[nt] = *(const short8*)&Wl[wn * 32 + nt * 16 + l15][rc];
        #pragma unroll
        for (int mt = 0; mt < 4; ++mt)
            #pragma unroll
            for (int nt = 0; nt < 2; ++nt)
                acc[mt][nt] = __builtin_amdgcn_mfma_f32_16x16x32_bf16(af[mt], wf[nt], acc[mt][nt], 0, 0, 0);
    }

    #pragma unroll
    for (int mt = 0; mt < 4; ++mt) {
        #pragma unroll
        for (int nt = 0; nt < 2; ++nt) {
            #pragma unroll
            for (int r = 0; r < 4; ++r) {
                int m = m0 + wm * 64 + mt * 16 + quad * 4 + r;
                int n = n0 + wn * 32 + nt * 16 + l15;
                float v2 = acc[mt][nt][r] + bias[n];
                if (EPI == 0) {
                    outb[(size_t)m * ldo + n] = f2bf(v2);
                } else if (EPI == 1) {
                    float g = 0.5f * v2 * (1.0f + erff(v2 * 0.70710678118654752f));
                    outb[(size_t)m * ldo + n] = f2bf(g);
                } else if (EPI == 2) {
                    int win = m / 49, np = m % 49;
                    int b = win >> 6, wl = win & 63;
                    int wh = wl >> 3, ww = wl & 7;
                    int i = np / 7, j = np % 7;
                    int pr = (wh * 7 + i + 3) % 56;
                    int pc = (ww * 7 + j + 3) % 56;
                    size_t dst = ((size_t)b * 3136 + (size_t)(pr * 56 + pc)) * 192 + n;
                    outf[dst] = resid[dst] + v2;
                } else {
                    size_t dst = (size_t)(mbase + m) * ldo + n;
                    outf[dst] = resid[dst] + v2;
                }
            }
        }
    }
}

// ---------------- MFMA windowed attention, S^T formulation (round-0 form) ----------
// 3 waves/block, one (window, head) per wave. S^T = K·Qs^T (acc-init = bias+mask table),
// softmax over keys = in-lane + 2 shfl, P normalized+packed -> Pb (b64 writes, row-major
// [query][key]), O = Pb·V with V B-frags gathered from 576-wide qkv. No barriers.
__global__ __launch_bounds__(192) void attn_kernel(const unsigned short* __restrict__ qkv,
                                                   const float* __restrict__ tbl,
                                                   unsigned short* __restrict__ awin) {
    __shared__ __align__(16) unsigned short Pb[3][64][72];
    int w = blockIdx.x >> 1;
    int hb = (blockIdx.x & 1) * 3;
    int hl = threadIdx.x >> 6;
    int h = hb + hl;
    int lane = threadIdx.x & 63;
    int quad = lane >> 4, l15 = lane & 15;
    const unsigned short* base = qkv + (size_t)w * 49 * 576;
    int wl = w & 63;
    int cls = ((wl >> 3) == 7 ? 2 : 0) + ((wl & 7) == 7 ? 1 : 0);
    const float* tb = tbl + (size_t)(cls * 6 + h) * 4096;

    // A = K rows, B = Q rows (q pre-scaled into qkv_w/qkv_b). Rows 49..63 are masked by
    // tbl=-3e38 but must read FINITE data: clamp to row 48 (past-the-end rows of the last
    // window would read unpoison-dependent workspace -> Inf/NaN risk otherwise).
    short8 kf[4], qf[4];
    #pragma unroll
    for (int mt = 0; mt < 4; ++mt) {
        int krow = mt * 16 + l15;
        krow = krow < 49 ? krow : 48;
        kf[mt] = *(const short8*)(base + (size_t)krow * 576 + 192 + h * 32 + quad * 8);
    }
    #pragma unroll
    for (int nt = 0; nt < 4; ++nt) {
        int qrow = nt * 16 + l15;
        qrow = qrow < 49 ? qrow : 48;
        qf[nt] = *(const short8*)(base + (size_t)qrow * 576 + h * 32 + quad * 8);
    }

    floatx4 S[4][4];
    #pragma unroll
    for (int mt = 0; mt < 4; ++mt)
        #pragma unroll
        for (int nt = 0; nt < 4; ++nt) {
            floatx4 cinit = *(const floatx4*)(tb + (nt * 16 + l15) * 64 + mt * 16 + quad * 4);
            S[mt][nt] = __builtin_amdgcn_mfma_f32_16x16x32_bf16(kf[mt], qf[nt], cinit, 0, 0, 0);
        }

    // exp (no max-sub: scores bounded ~±1; masked=-100 -> 0; key-pad=-3e38 -> 0)
    #pragma unroll
    for (int mt = 0; mt < 4; ++mt)
        #pragma unroll
        for (int nt = 0; nt < 4; ++nt)
            #pragma unroll
            for (int rr = 0; rr < 4; ++rr)
                S[mt][nt][rr] = __expf(S[mt][nt][rr]);

    // per-query sums: in-lane over (mt,rr), then reduce 4 quads
    float rinv[4];
    #pragma unroll
    for (int nt = 0; nt < 4; ++nt) {
        float s = 0.f;
        #pragma unroll
        for (int mt = 0; mt < 4; ++mt)
            s += (S[mt][nt][0] + S[mt][nt][1]) + (S[mt][nt][2] + S[mt][nt][3]);
        s += __shfl_xor(s, 16);
        s += __shfl_xor(s, 32);
        rinv[nt] = 1.0f / s;
    }

    // normalize + pack 4 consecutive keys -> b64 write, Pb row-major [query][key]
    #pragma unroll
    for (int mt = 0; mt < 4; ++mt) {
        #pragma unroll
        for (int nt = 0; nt < 4; ++nt) {
            __hip_bfloat162 p0 = __float22bfloat162_rn(
                make_float2(S[mt][nt][0] * rinv[nt], S[mt][nt][1] * rinv[nt]));
            __hip_bfloat162 p1 = __float22bfloat162_rn(
                make_float2(S[mt][nt][2] * rinv[nt], S[mt][nt][3] * rinv[nt]));
            union { __hip_bfloat162 h2[2]; uint2 u; } pk;
            pk.h2[0] = p0;
            pk.h2[1] = p1;
            *(uint2*)&Pb[hl][nt * 16 + l15][mt * 16 + quad * 4] = pk.u;
        }
    }

    // O = Pb · V ; V B-frags from global: lane l15 -> d, reg j -> key (imm offsets j*1152B)
    floatx4 O[4][2];
    floatx4 zero = {0.f, 0.f, 0.f, 0.f};
    #pragma unroll
    for (int mt = 0; mt < 4; ++mt)
        #pragma unroll
        for (int nt = 0; nt < 2; ++nt) O[mt][nt] = zero;
    #pragma unroll
    for (int ks = 0; ks < 2; ++ks) {
        short8 vf[2];
        #pragma unroll
        for (int nt = 0; nt < 2; ++nt) {
            const unsigned short* vb =
                base + (size_t)(ks * 32 + quad * 8) * 576 + 384 + h * 32 + nt * 16 + l15;
            #pragma unroll
            for (int j = 0; j < 8; ++j) vf[nt][j] = (short)vb[(size_t)j * 576];
        }
        #pragma unroll
        for (int mt = 0; mt < 4; ++mt) {
            short8 pf = *(const short8*)&Pb[hl][mt * 16 + l15][ks * 32 + quad * 8];
            #pragma unroll
            for (int nt = 0; nt < 2; ++nt)
                O[mt][nt] = __builtin_amdgcn_mfma_f32_16x16x32_bf16(pf, vf[nt], O[mt][nt], 0, 0, 0);
        }
    }
    #pragma unroll
    for (int mt = 0; mt < 4; ++mt) {
        #pragma unroll
        for (int rr = 0; rr < 4; ++rr) {
            int q = mt * 16 + quad * 4 + rr;
            if (q < 49) {
                #pragma unroll
                for (int nt = 0; nt < 2; ++nt)
                    awin[((size_t)w * 49 + q) * 192 + h * 32 + nt * 16 + l15] =
                        f2bf(O[mt][nt][rr]);
            }
        }
    }
}

extern "C" void kernel_launch(void* const* d_in, const int* in_sizes, int n_in,
                              void* d_out, int out_size, void* d_ws, size_t ws_size,
                              hipStream_t stream) {
    const float* x      = (const float*)d_in[0];
    const float* n1g    = (const float*)d_in[1];
    const float* n1b    = (const float*)d_in[2];
    const float* qkv_w  = (const float*)d_in[3];
    const float* qkv_b  = (const float*)d_in[4];
    const float* btab   = (const float*)d_in[5];
    const float* proj_w = (const float*)d_in[6];
    const float* proj_b = (const float*)d_in[7];
    const float* n2g    = (const float*)d_in[8];
    const float* n2b    = (const float*)d_in[9];
    const float* fc1_w  = (const float*)d_in[10];
    const float* fc1_b  = (const float*)d_in[11];
    const float* fc2_w  = (const float*)d_in[12];
    const float* fc2_b  = (const float*)d_in[13];
    float* out = (float*)d_out;

    char* p = (char*)d_ws;
    size_t off = 0;
    auto alloc = [&](size_t bytes) {
        char* r = p + off;
        off = (off + bytes + 255) & ~(size_t)255;
        return r;
    };
    unsigned short* wq   = (unsigned short*)alloc((size_t)576 * 192 * 2);
    unsigned short* wp   = (unsigned short*)alloc((size_t)192 * 192 * 2);
    unsigned short* w1   = (unsigned short*)alloc((size_t)768 * 192 * 2);
    unsigned short* w2   = (unsigned short*)alloc((size_t)192 * 768 * 2);
    unsigned short* hwin = (unsigned short*)alloc((size_t)200704 * 192 * 2);  // reused: awin
    unsigned short* qkvb = (unsigned short*)alloc((size_t)200704 * 576 * 2);  // reused: h2
    float*          xres = (float*)alloc((size_t)200704 * 192 * 4);
    unsigned short* g1   = (unsigned short*)alloc((size_t)50176 * 768 * 2);
    if (ws_size < off) return;
    // tbl + scaled qkv bias live in g1's region (g1 only used later, stream-ordered)
    float* tbl   = (float*)g1;              // 98304 floats
    float* qkvbs = (float*)g1 + 98304;      // 576 floats

    const float scale = 0.17677669529663687f;  // 32^-0.5, folded into q
    cvt_kernel<<<432, 256, 0, stream>>>(qkv_w, wq, 110592, 36864, scale);
    cvt_kernel<<<144, 256, 0, stream>>>(proj_w, wp, 36864, 0, 1.0f);
    cvt_kernel<<<576, 256, 0, stream>>>(fc1_w, w1, 147456, 0, 1.0f);
    cvt_kernel<<<576, 256, 0, stream>>>(fc2_w, w2, 147456, 0, 1.0f);
    biasscale_kernel<<<3, 256, 0, stream>>>(qkv_b, qkvbs, 576, 192, scale);
    bmt_kernel<<<384, 256, 0, stream>>>(btab, tbl);

    ln_kernel<<<50176, 256, 0, stream>>>(x, n1g, n1b, hwin, 0);
    gemm_nt<0><<<14112, 256, 0, stream>>>(hwin, wq, qkvbs, 192, 576, 0, 9,
                                          qkvb, nullptr, nullptr);
    attn_kernel<<<8192, 192, 0, stream>>>(qkvb, tbl, hwin /* awin reuse */);
    gemm_nt<2><<<4704, 256, 0, stream>>>(hwin, wp, proj_b, 192, 192, 0, 3,
                                         nullptr, xres, x);
    unsigned short* h2 = qkvb;
    ln_kernel<<<50176, 256, 0, stream>>>(xres, n2g, n2b, h2, 1);
    for (int c = 0; c < 4; ++c) {
        int mb = c * 50176;
        gemm_nt<1><<<4704, 256, 0, stream>>>(h2 + (size_t)mb * 192, w1, fc1_b, 192, 768, 0, 12,
                                             g1, nullptr, nullptr);
        gemm_nt<3><<<1176, 256, 0, stream>>>(g1, w2, fc2_b, 768, 192, mb, 3,
                                             nullptr, out, xres);
    }
}

// Round 13
// 993.133 us; speedup vs baseline: 1.0478x; 1.0478x over previous
//
#include <hip/hip_runtime.h>
#include <hip/hip_bf16.h>
#include <math.h>

typedef __attribute__((ext_vector_type(8))) short short8;
typedef __attribute__((ext_vector_type(4))) float floatx4;

__device__ __forceinline__ float bf2f(unsigned short u) {
    union { unsigned int i; float f; } v;
    v.i = ((unsigned int)u) << 16;
    return v.f;
}
__device__ __forceinline__ unsigned short f2bf(float f) {
    union { float f; unsigned int i; } v;
    v.f = f;
    return (unsigned short)((v.i + 0x7FFFu + ((v.i >> 16) & 1u)) >> 16);
}
__device__ __forceinline__ void async16(const void* g, void* l) {
    __builtin_amdgcn_global_load_lds((const __attribute__((address_space(1))) void*)g,
                                     (__attribute__((address_space(3))) void*)l, 16, 0, 0);
}

// ---------------- all four weight matrices fp32 -> bf16 in ONE launch ----------------
// segments: [0,110592) qkv_w (first 36864 scaled by q-scale); [.. ,147456) proj_w;
// [..,294912) fc1_w; [..,442368) fc2_w.  Grid 1728 x 256.
__global__ __launch_bounds__(256) void cvt4_kernel(const float* __restrict__ qw,
                                                   const float* __restrict__ pw,
                                                   const float* __restrict__ f1,
                                                   const float* __restrict__ f2,
                                                   unsigned short* __restrict__ dq,
                                                   unsigned short* __restrict__ dp,
                                                   unsigned short* __restrict__ d1,
                                                   unsigned short* __restrict__ d2,
                                                   float scale) {
    int i = blockIdx.x * 256 + threadIdx.x;
    if (i < 110592) {
        dq[i] = f2bf(qw[i] * (i < 36864 ? scale : 1.0f));
    } else if (i < 147456) {
        int j = i - 110592;
        dp[j] = f2bf(pw[j]);
    } else if (i < 294912) {
        int j = i - 147456;
        d1[j] = f2bf(f1[j]);
    } else {
        int j = i - 294912;
        d2[j] = f2bf(f2[j]);
    }
}
__global__ __launch_bounds__(256) void biasscale_kernel(const float* __restrict__ s,
                                                        float* __restrict__ d, int n,
                                                        int cut, float scale) {
    int i = blockIdx.x * 256 + threadIdx.x;
    if (i < n) d[i] = s[i] * (i < cut ? scale : 1.0f);
}

// ---------------- bias+mask accumulator-init table ----------------
// tbl[cls][h][query 64][key 64] fp32. key>=49 -> -3e38 (pad), query>=49 -> 0 (unused).
// cls = (wh==7)*2 + (ww==7): mask regions only differ at the bottom/right window row/col.
__global__ __launch_bounds__(256) void bmt_kernel(const float* __restrict__ btab,
                                                  float* __restrict__ tbl) {
    int idx = blockIdx.x * 256 + threadIdx.x;  // < 4*6*64*64
    int key = idx & 63;
    int q = (idx >> 6) & 63;
    int h = (idx >> 12) % 6;
    int cls = idx / (4096 * 6);
    float v;
    if (key >= 49) v = -3.0e38f;
    else if (q >= 49) v = 0.0f;
    else {
        int qi = q / 7, qj = q % 7, ki = key / 7, kj = key % 7;
        v = btab[((qi - ki + 6) * 13 + (qj - kj + 6)) * 6 + h];
        int whT = (cls >> 1) & 1, wwT = cls & 1;
        int rq = (whT ? (qi < 4 ? 1 : 2) : 0) * 3 + (wwT ? (qj < 4 ? 1 : 2) : 0);
        int rk = (whT ? (ki < 4 ? 1 : 2) : 0) * 3 + (wwT ? (kj < 4 ? 1 : 2) : 0);
        if (rq != rk) v -= 100.0f;
    }
    tbl[idx] = v;
}

// ---------------- LayerNorm over C=192, one wave per row ----------------
__global__ __launch_bounds__(256) void ln_kernel(const float* __restrict__ src,
                                                 const float* __restrict__ gw,
                                                 const float* __restrict__ bw,
                                                 unsigned short* __restrict__ dst,
                                                 int mode) {
    int o = blockIdx.x * 4 + (threadIdx.x >> 6);
    int lane = threadIdx.x & 63;
    size_t srow;
    if (mode == 0) {
        int win = o / 49, n = o % 49;
        int b = win >> 6, wl = win & 63;
        int wh = wl >> 3, ww = wl & 7;
        int i = n / 7, j = n % 7;
        int pr = (wh * 7 + i + 3) % 56;   // roll(-3)
        int pc = (ww * 7 + j + 3) % 56;
        srow = ((size_t)b * 3136 + (size_t)(pr * 56 + pc)) * 192;
    } else {
        srow = (size_t)o * 192;
    }
    float v0 = src[srow + lane];
    float v1 = src[srow + lane + 64];
    float v2 = src[srow + lane + 128];
    float s = v0 + v1 + v2;
    float s2 = v0 * v0 + v1 * v1 + v2 * v2;
    #pragma unroll
    for (int off = 32; off > 0; off >>= 1) {
        s += __shfl_xor(s, off);
        s2 += __shfl_xor(s2, off);
    }
    float mean = s * (1.0f / 192.0f);
    float var = s2 * (1.0f / 192.0f) - mean * mean;
    float inv = rsqrtf(var + 1e-5f);
    size_t drow = (size_t)o * 192;
    dst[drow + lane]       = f2bf((v0 - mean) * inv * gw[lane]       + bw[lane]);
    dst[drow + lane + 64]  = f2bf((v1 - mean) * inv * gw[lane + 64]  + bw[lane + 64]);
    dst[drow + lane + 128] = f2bf((v2 - mean) * inv * gw[lane + 128] + bw[lane + 128]);
}

// ---------------- GEMM: C[m][n] = sum_k A[m][k]*W[n][k] (+bias, epilogue) ----------
// R8 structure (measured best): 12KB LDS single-buffer, 2 syncs/step, XCD-grouping
// swizzle (qkv FETCH 314->38.5MB). LDS K-slot XOR kept from R9 (measured neutral:
// SQ_LDS_BANK_CONFLICT is structural for 16B-aligned b128 -- 8 possible bank starts --
// and its ~10%-of-cycles cost is TLP-hidden; do not chase further).
template <int EPI>
__global__ __launch_bounds__(256) void gemm_nt(const unsigned short* __restrict__ A,
                                               const unsigned short* __restrict__ W,
                                               const float* __restrict__ bias,
                                               int K, int ldo, int mbase, int gx,
                                               unsigned short* __restrict__ outb,
                                               float* __restrict__ outf,
                                               const float* __restrict__ resid) {
    __shared__ __align__(16) unsigned short Al[128][32];
    __shared__ __align__(16) unsigned short Wl[64][32];
    int tid = threadIdx.x;
    int lane = tid & 63;
    int wv = tid >> 6;
    int wm = wv >> 1, wn = wv & 1;
    // XCD-grouping swizzle: per-XCD contiguous virtual id (grid always % 8 == 0)
    int bid = blockIdx.x;
    int v = (bid & 7) * ((int)gridDim.x >> 3) + (bid >> 3);
    int m0 = (v / gx) * 128;
    int n0 = (v % gx) * 64;
    int quad = lane >> 4, l15 = lane & 15;

    int srow = lane >> 2;
    int scol = ((lane & 3) ^ (srow & 3)) * 8;   // pre-swizzled global source K-slot
    const unsigned short* aP0 = A + (size_t)(m0 + wv * 32 + srow) * K + scol;
    const unsigned short* aP1 = aP0 + (size_t)16 * K;
    const unsigned short* wP  = W + (size_t)(n0 + wv * 16 + srow) * K + scol;
    unsigned short* lA0 = &Al[wv * 32][0];
    unsigned short* lA1 = &Al[wv * 32 + 16][0];
    unsigned short* lW  = &Wl[wv * 16][0];

    floatx4 acc[4][2];
    floatx4 zero = {0.f, 0.f, 0.f, 0.f};
    #pragma unroll
    for (int a = 0; a < 4; ++a)
        #pragma unroll
        for (int b = 0; b < 2; ++b) acc[a][b] = zero;

    int rc = (quad ^ (l15 & 3)) * 8;            // swizzled read K-slot
    for (int kt = 0; kt < K; kt += 32) {
        __syncthreads();
        async16(aP0 + kt, lA0);
        async16(aP1 + kt, lA1);
        async16(wP + kt, lW);
        __syncthreads();
        short8 af[4], wf[2];
        #pragma unroll
        for (int mt = 0; mt < 4; ++mt)
            af[mt] = *(const short8*)&Al[wm * 64 + mt * 16 + l15][rc];
        #pragma unroll
        for (int nt = 0; nt < 2; ++nt)
            wf[nt] = *(const short8*)&Wl[wn * 32 + nt * 16 + l15][rc];
        #pragma unroll
        for (int mt = 0; mt < 4; ++mt)
            #pragma unroll
            for (int nt = 0; nt < 2; ++nt)
                acc[mt][nt] = __builtin_amdgcn_mfma_f32_16x16x32_bf16(af[mt], wf[nt], acc[mt][nt], 0, 0, 0);
    }

    #pragma unroll
    for (int mt = 0; mt < 4; ++mt) {
        #pragma unroll
        for (int nt = 0; nt < 2; ++nt) {
            #pragma unroll
            for (int r = 0; r < 4; ++r) {
                int m = m0 + wm * 64 + mt * 16 + quad * 4 + r;
                int n = n0 + wn * 32 + nt * 16 + l15;
                float v2 = acc[mt][nt][r] + bias[n];
                if (EPI == 0) {
                    outb[(size_t)m * ldo + n] = f2bf(v2);
                } else if (EPI == 1) {
                    float g = 0.5f * v2 * (1.0f + erff(v2 * 0.70710678118654752f));
                    outb[(size_t)m * ldo + n] = f2bf(g);
                } else if (EPI == 2) {
                    int win = m / 49, np = m % 49;
                    int b = win >> 6, wl = win & 63;
                    int wh = wl >> 3, ww = wl & 7;
                    int i = np / 7, j = np % 7;
                    int pr = (wh * 7 + i + 3) % 56;
                    int pc = (ww * 7 + j + 3) % 56;
                    size_t dst = ((size_t)b * 3136 + (size_t)(pr * 56 + pc)) * 192 + n;
                    outf[dst] = resid[dst] + v2;
                } else {
                    size_t dst = (size_t)(mbase + m) * ldo + n;
                    outf[dst] = resid[dst] + v2;
                }
            }
        }
    }
}

// ---------------- MFMA windowed attention, S^T formulation (round-0 form) ----------
// 3 waves/block, one (window, head) per wave. S^T = K·Qs^T (acc-init = bias+mask table),
// softmax over keys = in-lane + 2 shfl, P normalized+packed -> Pb (b64 writes, row-major
// [query][key]), O = Pb·V with V B-frags gathered from 576-wide qkv. No barriers.
__global__ __launch_bounds__(192) void attn_kernel(const unsigned short* __restrict__ qkv,
                                                   const float* __restrict__ tbl,
                                                   unsigned short* __restrict__ awin) {
    __shared__ __align__(16) unsigned short Pb[3][64][72];
    int w = blockIdx.x >> 1;
    int hb = (blockIdx.x & 1) * 3;
    int hl = threadIdx.x >> 6;
    int h = hb + hl;
    int lane = threadIdx.x & 63;
    int quad = lane >> 4, l15 = lane & 15;
    const unsigned short* base = qkv + (size_t)w * 49 * 576;
    int wl = w & 63;
    int cls = ((wl >> 3) == 7 ? 2 : 0) + ((wl & 7) == 7 ? 1 : 0);
    const float* tb = tbl + (size_t)(cls * 6 + h) * 4096;

    // A = K rows, B = Q rows (q pre-scaled into qkv_w/qkv_b). Rows 49..63 are masked by
    // tbl=-3e38 but must read FINITE data: clamp to row 48 (past-the-end rows of the last
    // window would read unpoison-dependent workspace -> Inf/NaN risk otherwise).
    short8 kf[4], qf[4];
    #pragma unroll
    for (int mt = 0; mt < 4; ++mt) {
        int krow = mt * 16 + l15;
        krow = krow < 49 ? krow : 48;
        kf[mt] = *(const short8*)(base + (size_t)krow * 576 + 192 + h * 32 + quad * 8);
    }
    #pragma unroll
    for (int nt = 0; nt < 4; ++nt) {
        int qrow = nt * 16 + l15;
        qrow = qrow < 49 ? qrow : 48;
        qf[nt] = *(const short8*)(base + (size_t)qrow * 576 + h * 32 + quad * 8);
    }

    floatx4 S[4][4];
    #pragma unroll
    for (int mt = 0; mt < 4; ++mt)
        #pragma unroll
        for (int nt = 0; nt < 4; ++nt) {
            floatx4 cinit = *(const floatx4*)(tb + (nt * 16 + l15) * 64 + mt * 16 + quad * 4);
            S[mt][nt] = __builtin_amdgcn_mfma_f32_16x16x32_bf16(kf[mt], qf[nt], cinit, 0, 0, 0);
        }

    // exp (no max-sub: scores bounded ~±1; masked=-100 -> 0; key-pad=-3e38 -> 0)
    #pragma unroll
    for (int mt = 0; mt < 4; ++mt)
        #pragma unroll
        for (int nt = 0; nt < 4; ++nt)
            #pragma unroll
            for (int rr = 0; rr < 4; ++rr)
                S[mt][nt][rr] = __expf(S[mt][nt][rr]);

    // per-query sums: in-lane over (mt,rr), then reduce 4 quads
    float rinv[4];
    #pragma unroll
    for (int nt = 0; nt < 4; ++nt) {
        float s = 0.f;
        #pragma unroll
        for (int mt = 0; mt < 4; ++mt)
            s += (S[mt][nt][0] + S[mt][nt][1]) + (S[mt][nt][2] + S[mt][nt][3]);
        s += __shfl_xor(s, 16);
        s += __shfl_xor(s, 32);
        rinv[nt] = 1.0f / s;
    }

    // normalize + pack 4 consecutive keys -> b64 write, Pb row-major [query][key]
    #pragma unroll
    for (int mt = 0; mt < 4; ++mt) {
        #pragma unroll
        for (int nt = 0; nt < 4; ++nt) {
            __hip_bfloat162 p0 = __float22bfloat162_rn(
                make_float2(S[mt][nt][0] * rinv[nt], S[mt][nt][1] * rinv[nt]));
            __hip_bfloat162 p1 = __float22bfloat162_rn(
                make_float2(S[mt][nt][2] * rinv[nt], S[mt][nt][3] * rinv[nt]));
            union { __hip_bfloat162 h2[2]; uint2 u; } pk;
            pk.h2[0] = p0;
            pk.h2[1] = p1;
            *(uint2*)&Pb[hl][nt * 16 + l15][mt * 16 + quad * 4] = pk.u;
        }
    }

    // O = Pb · V ; V B-frags from global: lane l15 -> d, reg j -> key (imm offsets j*1152B)
    floatx4 O[4][2];
    floatx4 zero = {0.f, 0.f, 0.f, 0.f};
    #pragma unroll
    for (int mt = 0; mt < 4; ++mt)
        #pragma unroll
        for (int nt = 0; nt < 2; ++nt) O[mt][nt] = zero;
    #pragma unroll
    for (int ks = 0; ks < 2; ++ks) {
        short8 vf[2];
        #pragma unroll
        for (int nt = 0; nt < 2; ++nt) {
            const unsigned short* vb =
                base + (size_t)(ks * 32 + quad * 8) * 576 + 384 + h * 32 + nt * 16 + l15;
            #pragma unroll
            for (int j = 0; j < 8; ++j) vf[nt][j] = (short)vb[(size_t)j * 576];
        }
        #pragma unroll
        for (int mt = 0; mt < 4; ++mt) {
            short8 pf = *(const short8*)&Pb[hl][mt * 16 + l15][ks * 32 + quad * 8];
            #pragma unroll
            for (int nt = 0; nt < 2; ++nt)
                O[mt][nt] = __builtin_amdgcn_mfma_f32_16x16x32_bf16(pf, vf[nt], O[mt][nt], 0, 0, 0);
        }
    }
    #pragma unroll
    for (int mt = 0; mt < 4; ++mt) {
        #pragma unroll
        for (int rr = 0; rr < 4; ++rr) {
            int q = mt * 16 + quad * 4 + rr;
            if (q < 49) {
                #pragma unroll
                for (int nt = 0; nt < 2; ++nt)
                    awin[((size_t)w * 49 + q) * 192 + h * 32 + nt * 16 + l15] =
                        f2bf(O[mt][nt][rr]);
            }
        }
    }
}

extern "C" void kernel_launch(void* const* d_in, const int* in_sizes, int n_in,
                              void* d_out, int out_size, void* d_ws, size_t ws_size,
                              hipStream_t stream) {
    const float* x      = (const float*)d_in[0];
    const float* n1g    = (const float*)d_in[1];
    const float* n1b    = (const float*)d_in[2];
    const float* qkv_w  = (const float*)d_in[3];
    const float* qkv_b  = (const float*)d_in[4];
    const float* btab   = (const float*)d_in[5];
    const float* proj_w = (const float*)d_in[6];
    const float* proj_b = (const float*)d_in[7];
    const float* n2g    = (const float*)d_in[8];
    const float* n2b    = (const float*)d_in[9];
    const float* fc1_w  = (const float*)d_in[10];
    const float* fc1_b  = (const float*)d_in[11];
    const float* fc2_w  = (const float*)d_in[12];
    const float* fc2_b  = (const float*)d_in[13];
    float* out = (float*)d_out;

    char* p = (char*)d_ws;
    size_t off = 0;
    auto alloc = [&](size_t bytes) {
        char* r = p + off;
        off = (off + bytes + 255) & ~(size_t)255;
        return r;
    };
    unsigned short* wq   = (unsigned short*)alloc((size_t)576 * 192 * 2);
    unsigned short* wp   = (unsigned short*)alloc((size_t)192 * 192 * 2);
    unsigned short* w1   = (unsigned short*)alloc((size_t)768 * 192 * 2);
    unsigned short* w2   = (unsigned short*)alloc((size_t)192 * 768 * 2);
    unsigned short* hwin = (unsigned short*)alloc((size_t)200704 * 192 * 2);  // reused: awin
    unsigned short* qkvb = (unsigned short*)alloc((size_t)200704 * 576 * 2);  // reused: h2 + g1 tail
    float*          xres = (float*)alloc((size_t)200704 * 192 * 4);
    unsigned short* g1r  = (unsigned short*)alloc((size_t)50176 * 768 * 2);
    if (ws_size < off) return;
    // tbl + scaled qkv bias live in g1r's region (only needed through the attn phase)
    float* tbl   = (float*)g1r;             // 98304 floats
    float* qkvbs = (float*)g1r + 98304;     // 576 floats

    const float scale = 0.17677669529663687f;  // 32^-0.5, folded into q
    cvt4_kernel<<<1728, 256, 0, stream>>>(qkv_w, proj_w, fc1_w, fc2_w,
                                          wq, wp, w1, w2, scale);
    biasscale_kernel<<<3, 256, 0, stream>>>(qkv_b, qkvbs, 576, 192, scale);
    bmt_kernel<<<384, 256, 0, stream>>>(btab, tbl);

    ln_kernel<<<50176, 256, 0, stream>>>(x, n1g, n1b, hwin, 0);
    gemm_nt<0><<<14112, 256, 0, stream>>>(hwin, wq, qkvbs, 192, 576, 0, 9,
                                          qkvb, nullptr, nullptr);
    attn_kernel<<<8192, 192, 0, stream>>>(qkvb, tbl, hwin /* awin reuse */);
    gemm_nt<2><<<4704, 256, 0, stream>>>(hwin, wp, proj_b, 192, 192, 0, 3,
                                         nullptr, xres, x);
    // MLP in 2 chunks (was 4): h2 = first 77MB of qkvb region; g1 buffer = its 154MB
    // tail (exactly 100352*768*2 B), both dead-data regions after attn.
    unsigned short* h2  = qkvb;
    unsigned short* g1b = qkvb + (size_t)200704 * 192;
    ln_kernel<<<50176, 256, 0, stream>>>(xres, n2g, n2b, h2, 1);
    for (int c = 0; c < 2; ++c) {
        int mb = c * 100352;
        gemm_nt<1><<<9408, 256, 0, stream>>>(h2 + (size_t)mb * 192, w1, fc1_b, 192, 768, 0, 12,
                                             g1b, nullptr, nullptr);
        gemm_nt<3><<<2352, 256, 0, stream>>>(g1b, w2, fc2_b, 768, 192, mb, 3,
                                             nullptr, out, xres);
    }
}